// Round 2
// baseline (328.822 us; speedup 1.0000x reference)
//
#include <hip/hip_runtime.h>
#include <hip/hip_bf16.h>

// RecurrentGCN (DCRNN cell, K=1) — edge_index/edge_weight mathematically unused.
// Per-node dense GRU with combined weights W = w[0]+w[1] (48x32), then 32->8
// output projection. This version is DTYPE-ADAPTIVE: it detects at runtime
// whether the float tensors are stored as f32 or bf16 (harness may convert),
// by checking whether low-16-bit halves of x's words are sane bf16 values.

#define N_NODES 500000
#define IN_DIM  16
#define HID     32
#define OUT_DIM 8
#define XH      48   // IN_DIM + HID

typedef unsigned int u32;
typedef unsigned short u16;

__device__ __forceinline__ float bfbits(u32 hi) {
    union { u32 x; float f; } t; t.x = hi; return t.f;
}
__device__ __forceinline__ float bflo(u32 u) { return bfbits(u << 16); }
__device__ __forceinline__ float bfhi(u32 u) { return bfbits(u & 0xffff0000u); }
__device__ __forceinline__ float bf2f(u16 s) { return bfbits(((u32)s) << 16); }
__device__ __forceinline__ u16 f2bf(float f) {
    union { float f; u32 x; } t; t.f = f;
    u32 x = t.x;
    return (u16)((x + 0x7fffu + ((x >> 16) & 1u)) >> 16);  // RNE
}

__global__ __launch_bounds__(256)
void rgcn_kernel(const void* __restrict__ xp_,   // [N,16]
                 const void* __restrict__ hp_,   // [N,32]
                 const void* __restrict__ wz_,   // [2,48,32]
                 const void* __restrict__ bz_,   // [32]
                 const void* __restrict__ wr_,
                 const void* __restrict__ br_,
                 const void* __restrict__ wh_,
                 const void* __restrict__ bh_,
                 const void* __restrict__ wl_,   // [32,8]
                 const void* __restrict__ bl_,   // [8]
                 void* __restrict__ dout_)       // out [N,8] ++ h_new [N,32]
{
    __shared__ float sWz[HID][XH];
    __shared__ float sWr[HID][XH];
    __shared__ float sWh[HID][XH];
    __shared__ float sWl[HID][OUT_DIM];
    __shared__ float sBz[HID], sBr[HID], sBh[HID], sBl[OUT_DIM];
    __shared__ int sF32;

    const int tid = threadIdx.x;

    // ---- dtype detection: if x were bf16, every 16-bit half is a sane value.
    // If x is f32, low halves are mantissa bits -> random exponent as bf16.
    if (tid == 0) {
        const u32* xw = (const u32*)xp_;
        int f = 0;
        for (int q = 0; q < 128; q++) {
            float lo = bflo(xw[q]);
            if (!(fabsf(lo) <= 1e6f)) { f = 1; break; }
        }
        sF32 = f;
    }
    __syncthreads();
    const bool F32 = (sF32 != 0);

    // ---- stage combined (w[0]+w[1]) weights transposed into LDS as f32
    if (F32) {
        const float* wz = (const float*)wz_; const float* wr = (const float*)wr_;
        const float* wh = (const float*)wh_; const float* wl = (const float*)wl_;
        const float* bz = (const float*)bz_; const float* br = (const float*)br_;
        const float* bh = (const float*)bh_; const float* bl = (const float*)bl_;
        for (int o = tid; o < HID * XH; o += 256) {
            int j = o / XH, k = o - j * XH;
            int src = k * HID + j;                  // [k][j] in each half
            sWz[j][k] = wz[src] + wz[XH * HID + src];
            sWr[j][k] = wr[src] + wr[XH * HID + src];
            sWh[j][k] = wh[src] + wh[XH * HID + src];
        }
        if (tid < HID * OUT_DIM) ((float*)sWl)[tid] = wl[tid];
        if (tid < HID) { sBz[tid] = bz[tid]; sBr[tid] = br[tid]; sBh[tid] = bh[tid]; }
        if (tid < OUT_DIM) sBl[tid] = bl[tid];
    } else {
        const u16* wz = (const u16*)wz_; const u16* wr = (const u16*)wr_;
        const u16* wh = (const u16*)wh_; const u16* wl = (const u16*)wl_;
        const u16* bz = (const u16*)bz_; const u16* br = (const u16*)br_;
        const u16* bh = (const u16*)bh_; const u16* bl = (const u16*)bl_;
        for (int o = tid; o < HID * XH; o += 256) {
            int j = o / XH, k = o - j * XH;
            int src = k * HID + j;
            sWz[j][k] = bf2f(wz[src]) + bf2f(wz[XH * HID + src]);
            sWr[j][k] = bf2f(wr[src]) + bf2f(wr[XH * HID + src]);
            sWh[j][k] = bf2f(wh[src]) + bf2f(wh[XH * HID + src]);
        }
        if (tid < HID * OUT_DIM) ((float*)sWl)[tid] = bf2f(wl[tid]);
        if (tid < HID) { sBz[tid] = bf2f(bz[tid]); sBr[tid] = bf2f(br[tid]); sBh[tid] = bf2f(bh[tid]); }
        if (tid < OUT_DIM) sBl[tid] = bf2f(bl[tid]);
    }
    __syncthreads();

    const int i = blockIdx.x * 256 + tid;
    if (i >= N_NODES) return;

    // ---- load x and h (vectorized, branch is wave-uniform)
    float xv[IN_DIM], hv[HID];
    if (F32) {
        const float4* xp = (const float4*)((const float*)xp_ + (size_t)i * IN_DIM);
#pragma unroll
        for (int q = 0; q < 4; q++) {
            float4 v = xp[q];
            xv[4*q+0] = v.x; xv[4*q+1] = v.y; xv[4*q+2] = v.z; xv[4*q+3] = v.w;
        }
        const float4* hp = (const float4*)((const float*)hp_ + (size_t)i * HID);
#pragma unroll
        for (int q = 0; q < 8; q++) {
            float4 v = hp[q];
            hv[4*q+0] = v.x; hv[4*q+1] = v.y; hv[4*q+2] = v.z; hv[4*q+3] = v.w;
        }
    } else {
        const uint4* xp = (const uint4*)((const u16*)xp_ + (size_t)i * IN_DIM);
        uint4 a = xp[0], b = xp[1];
        u32 wx[8] = {a.x, a.y, a.z, a.w, b.x, b.y, b.z, b.w};
#pragma unroll
        for (int q = 0; q < 8; q++) { xv[2*q] = bflo(wx[q]); xv[2*q+1] = bfhi(wx[q]); }
        const uint4* hp = (const uint4*)((const u16*)hp_ + (size_t)i * HID);
        uint4 c0 = hp[0], c1 = hp[1], c2 = hp[2], c3 = hp[3];
        u32 wh16[16] = {c0.x,c0.y,c0.z,c0.w, c1.x,c1.y,c1.z,c1.w,
                        c2.x,c2.y,c2.z,c2.w, c3.x,c3.y,c3.z,c3.w};
#pragma unroll
        for (int q = 0; q < 16; q++) { hv[2*q] = bflo(wh16[q]); hv[2*q+1] = bfhi(wh16[q]); }
    }

    // ---- pass 1: reset gate -> hr = h * r
    float hr[HID];
#pragma unroll 4
    for (int j = 0; j < HID; j++) {
        float acc = sBr[j];
#pragma unroll
        for (int k = 0; k < IN_DIM; k++) acc += xv[k] * sWr[j][k];
#pragma unroll
        for (int k = 0; k < HID; k++)    acc += hv[k] * sWr[j][IN_DIM + k];
        acc = fminf(fmaxf(acc, -30.f), 30.f);
        float rj = 1.f / (1.f + __expf(-acc));
        hr[j] = hv[j] * rj;
    }

    // ---- pass 2: z gate + candidate + h_new + fused output projection
    float oacc[OUT_DIM];
#pragma unroll
    for (int o = 0; o < OUT_DIM; o++) oacc[o] = sBl[o];

    float hn[HID];
#pragma unroll 2
    for (int j = 0; j < HID; j++) {
        float az = sBz[j], ah = sBh[j];
#pragma unroll
        for (int k = 0; k < IN_DIM; k++) {
            az += xv[k] * sWz[j][k];
            ah += xv[k] * sWh[j][k];
        }
#pragma unroll
        for (int k = 0; k < HID; k++) {
            az += hv[k] * sWz[j][IN_DIM + k];
            ah += hr[k] * sWh[j][IN_DIM + k];
        }
        az = fminf(fmaxf(az, -30.f), 30.f);
        ah = fminf(fmaxf(ah, -20.f), 20.f);
        float z  = 1.f / (1.f + __expf(-az));
        float e  = __expf(-2.f * ah);
        float ht = (1.f - e) / (1.f + e);
        float v  = z * hv[j] + (1.f - z) * ht;
        hn[j] = v;
        float rh = fmaxf(v, 0.f);
#pragma unroll
        for (int o = 0; o < OUT_DIM; o++) oacc[o] += rh * sWl[j][o];
    }

    // ---- stores
    if (F32) {
        float* outp = (float*)dout_;
        float* hnp  = outp + (size_t)N_NODES * OUT_DIM;
        float4* hd = (float4*)(hnp + (size_t)i * HID);
#pragma unroll
        for (int q = 0; q < 8; q++) {
            float4 v; v.x = hn[4*q]; v.y = hn[4*q+1]; v.z = hn[4*q+2]; v.w = hn[4*q+3];
            hd[q] = v;
        }
        float4* od = (float4*)(outp + (size_t)i * OUT_DIM);
        float4 o0, o1;
        o0.x = oacc[0]; o0.y = oacc[1]; o0.z = oacc[2]; o0.w = oacc[3];
        o1.x = oacc[4]; o1.y = oacc[5]; o1.z = oacc[6]; o1.w = oacc[7];
        od[0] = o0; od[1] = o1;
    } else {
        u16* outp = (u16*)dout_;
        u16* hnp  = outp + (size_t)N_NODES * OUT_DIM;
        __align__(16) u16 hb[HID];
#pragma unroll
        for (int j = 0; j < HID; j++) hb[j] = f2bf(hn[j]);
        uint4* hd = (uint4*)(hnp + (size_t)i * HID);
        const uint4* hs = (const uint4*)hb;
        hd[0] = hs[0]; hd[1] = hs[1]; hd[2] = hs[2]; hd[3] = hs[3];
        __align__(16) u16 ob[OUT_DIM];
#pragma unroll
        for (int o = 0; o < OUT_DIM; o++) ob[o] = f2bf(oacc[o]);
        *(uint4*)(outp + (size_t)i * OUT_DIM) = *(const uint4*)ob;
    }
}

extern "C" void kernel_launch(void* const* d_in, const int* in_sizes, int n_in,
                              void* d_out, int out_size, void* d_ws, size_t ws_size,
                              hipStream_t stream) {
    // setup_inputs() order:
    // 0 x, 1 edge_index(int32, unused), 2 edge_weight(unused), 3 h,
    // 4 w_z, 5 b_z, 6 w_r, 7 b_r, 8 w_h, 9 b_h, 10 w_lin, 11 b_lin
    const int block = 256;
    const int grid = (N_NODES + block - 1) / block;
    rgcn_kernel<<<grid, block, 0, stream>>>(
        d_in[0], d_in[3], d_in[4], d_in[5], d_in[6], d_in[7],
        d_in[8], d_in[9], d_in[10], d_in[11], d_out);
}